// Round 2
// baseline (258.104 us; speedup 1.0000x reference)
//
#include <hip/hip_runtime.h>
#include <hip/hip_bf16.h>

#define B_ 8
#define T_ 4096
#define D_ 512
#define L_ 128
#define H_ 8
#define Dh_ 64
#define Lh_ 16
#define M_ (B_*T_)          // 32768 rows
#define SCALE 0.125f        // rsqrt(Dh)

typedef __bf16 v8bf __attribute__((ext_vector_type(8)));
typedef float  v4f  __attribute__((ext_vector_type(4)));
typedef unsigned short u16;
typedef u16 v8u __attribute__((ext_vector_type(8)));

__device__ __forceinline__ float b2f(u16 h){
    unsigned int u = ((unsigned int)h) << 16;
    return __builtin_bit_cast(float, u);
}
__device__ __forceinline__ u16 f2bf(float f){
    unsigned int u = __builtin_bit_cast(unsigned int, f);
    u += 0x7FFFu + ((u >> 16) & 1u);   // RNE
    return (u16)(u >> 16);
}

// async global->LDS, 16B per lane; lds dest = wave-uniform base + lane*16
__device__ __forceinline__ void gload16(const u16* g, u16* l) {
    __builtin_amdgcn_global_load_lds(
        (const __attribute__((address_space(1))) unsigned int*)(g),
        (__attribute__((address_space(3))) unsigned int*)(l), 16, 0, 0);
}

// ---------------------------------------------------------------------------
// prep: one launch = X fp32->bf16 convert (blocks 0..8191) + 4 weight
// transposes fp32(rows x cols) -> bf16 (cols x rows) (blocks 8192..8831)
// ---------------------------------------------------------------------------
__global__ __launch_bounds__(256) void prep(
        const float* __restrict__ X,  const float* __restrict__ Wq,
        const float* __restrict__ Wk, const float* __restrict__ Wv,
        const float* __restrict__ Wo,
        u16* __restrict__ Xb, u16* __restrict__ WT, u16* __restrict__ OT)
{
    int bid = blockIdx.x;
    if (bid < 8192) {   // X convert: 8 elems / thread
        const size_t i = (size_t)bid * 256 + threadIdx.x;
        const float4* s = (const float4*)X + i * 2;
        float4 a = s[0], b = s[1];
        v8u o;
        o[0] = f2bf(a.x); o[1] = f2bf(a.y); o[2] = f2bf(a.z); o[3] = f2bf(a.w);
        o[4] = f2bf(b.x); o[5] = f2bf(b.y); o[6] = f2bf(b.z); o[7] = f2bf(b.w);
        *((v8u*)Xb + i) = o;
        return;
    }
    bid -= 8192;
    const float* src; u16* dst; int cols, bx, by;
    if (bid < 64)       { src = Wq; dst = WT;             cols = 128; bx = bid & 3;  by = bid >> 2; }
    else if (bid < 128) { src = Wk; dst = WT + 128 * 512; cols = 128; bid -= 64;  bx = bid & 3;  by = bid >> 2; }
    else if (bid < 384) { src = Wv; dst = WT + 256 * 512; cols = 512; bid -= 128; bx = bid & 15; by = bid >> 4; }
    else                { src = Wo; dst = OT;             cols = 512; bid -= 384; bx = bid & 15; by = bid >> 4; }
    __shared__ u16 tile[32][33];
    const int tx = threadIdx.x & 31, ty = threadIdx.x >> 5;
    const int c0 = bx * 32, r0 = by * 32;
    #pragma unroll
    for (int i = 0; i < 32; i += 8)
        tile[ty + i][tx] = f2bf(src[(size_t)(r0 + ty + i) * cols + c0 + tx]);
    __syncthreads();
    #pragma unroll
    for (int i = 0; i < 32; i += 8)
        dst[(size_t)(c0 + ty + i) * 512 + r0 + tx] = tile[tx][ty + i];
}

// ---------------------------------------------------------------------------
// P1/P5: MFMA bf16 GEMM.  2-phase software pipeline (T3 minimum recipe):
// double-buffered LDS; STAGE(kt+1 -> buf^1) issued BEFORE ds_read+MFMA of
// buf[cur]; single vmcnt(0) + raw s_barrier per K-step so next-tile loads
// overlap this tile's MFMAs.  XOR granule swizzle (pos = g ^ (row&7)).
// MODE 0: write QS=softmax(Q*s)(f32) / KE=exp(K*s)(bf16) / V(bf16).
// MODE 1: fp32 Out.  gn0 selects a pure column-type -> block-uniform epilogue.
// ---------------------------------------------------------------------------
template<int MODE>
__global__ __launch_bounds__(256) void gemm_mfma(
        const u16* __restrict__ A, const u16* __restrict__ Bt,
        float* __restrict__ Qo, u16* __restrict__ KEo,
        u16* __restrict__ Vo, float* __restrict__ OutF)
{
    __shared__ __align__(16) u16 As[2][128 * 64];   // row*64 + (g^(row&7))*8
    __shared__ __align__(16) u16 Bs[2][128 * 64];
    const int tid  = threadIdx.x;
    const int wave = tid >> 6, lane = tid & 63;
    const int wm = wave >> 1, wn = wave & 1;     // 2x2 waves, 64x64 each
    const int lm = lane & 15, quad = lane >> 4;
    const int gm0 = blockIdx.x * 128, gn0 = blockIdx.y * 128;

    const int srow0 = wave * 32 + (lane >> 3);   // staging row, + r*8
    const int sg    = lane & 7;                  // staging granule position

    v4f acc[4][4];
    #pragma unroll
    for (int i = 0; i < 4; i++)
        #pragma unroll
        for (int j = 0; j < 4; j++)
            acc[i][j] = (v4f){0.f, 0.f, 0.f, 0.f};

    // prologue: stage K-tile 0 into buffer 0
    {
        #pragma unroll
        for (int r = 0; r < 4; ++r) {
            const int row = srow0 + r * 8;
            const int col = ((sg ^ (row & 7)) << 3);
            gload16(&A [(size_t)(gm0 + row) * 512 + col], &As[0][(wave * 4 + r) * 512]);
            gload16(&Bt[(size_t)(gn0 + row) * 512 + col], &Bs[0][(wave * 4 + r) * 512]);
        }
        asm volatile("s_waitcnt vmcnt(0)" ::: "memory");
        __builtin_amdgcn_s_barrier();
    }

    for (int kt = 0; kt < 8; ++kt) {
        const int cur = kt & 1;
        if (kt < 7) {   // stage next K-tile into the other buffer (async)
            const int k0 = (kt + 1) * 64;
            #pragma unroll
            for (int r = 0; r < 4; ++r) {
                const int row = srow0 + r * 8;
                const int col = ((sg ^ (row & 7)) << 3) + k0;
                gload16(&A [(size_t)(gm0 + row) * 512 + col], &As[cur ^ 1][(wave * 4 + r) * 512]);
                gload16(&Bt[(size_t)(gn0 + row) * 512 + col], &Bs[cur ^ 1][(wave * 4 + r) * 512]);
            }
        }
        v8bf af[2][4], bfr[2][4];
        #pragma unroll
        for (int ks = 0; ks < 2; ks++)
            #pragma unroll
            for (int mi = 0; mi < 4; mi++) {
                const int g  = ks * 4 + quad;
                const int ra = wm * 64 + mi * 16 + lm;
                const int rb = wn * 64 + mi * 16 + lm;
                af [ks][mi] = *(const v8bf*)&As[cur][ra * 64 + ((g ^ (ra & 7)) << 3)];
                bfr[ks][mi] = *(const v8bf*)&Bs[cur][rb * 64 + ((g ^ (rb & 7)) << 3)];
            }
        #pragma unroll
        for (int ks = 0; ks < 2; ks++)
            #pragma unroll
            for (int mi = 0; mi < 4; mi++)
                #pragma unroll
                for (int ni = 0; ni < 4; ni++)
                    acc[mi][ni] = __builtin_amdgcn_mfma_f32_16x16x32_bf16(
                                      af[ks][mi], bfr[ks][ni], acc[mi][ni], 0, 0, 0);
        if (kt < 7) {
            // drain next-tile loads (they overlapped the MFMAs above), then
            // barrier: buf[cur^1] ready, buf[cur] free for restage.
            asm volatile("s_waitcnt vmcnt(0)" ::: "memory");
            __builtin_amdgcn_s_barrier();
        }
    }

    if (MODE == 1) {
        #pragma unroll
        for (int mi = 0; mi < 4; mi++)
          #pragma unroll
          for (int ni = 0; ni < 4; ni++)
            #pragma unroll
            for (int i = 0; i < 4; i++) {
                int row = gm0 + wm * 64 + mi * 16 + quad * 4 + i;
                int col = gn0 + wn * 64 + ni * 16 + lm;
                OutF[(size_t)row * 512 + col] = acc[mi][ni][i];
            }
    } else if (gn0 == 0) {
        // Q block: fold the row-softmax here. For fixed (mi,ni,i) the 16 lanes
        // lm hold exactly one head's Lh=16 values -> 16-lane shfl reduce.
        #pragma unroll
        for (int mi = 0; mi < 4; mi++)
          #pragma unroll
          for (int ni = 0; ni < 4; ni++)
            #pragma unroll
            for (int i = 0; i < 4; i++) {
                int row = gm0 + wm * 64 + mi * 16 + quad * 4 + i;
                int col = wn * 64 + ni * 16 + lm;
                float qv = acc[mi][ni][i] * SCALE;
                float m = qv;
                #pragma unroll
                for (int off = 1; off < 16; off <<= 1) m = fmaxf(m, __shfl_xor(m, off));
                float e = __expf(qv - m);
                float s = e;
                #pragma unroll
                for (int off = 1; off < 16; off <<= 1) s += __shfl_xor(s, off);
                Qo[(size_t)row * 128 + col] = e / s;
            }
    } else if (gn0 == 128) {
        #pragma unroll
        for (int mi = 0; mi < 4; mi++)
          #pragma unroll
          for (int ni = 0; ni < 4; ni++)
            #pragma unroll
            for (int i = 0; i < 4; i++) {
                int row = gm0 + wm * 64 + mi * 16 + quad * 4 + i;
                int col = wn * 64 + ni * 16 + lm;
                KEo[(size_t)row * 128 + col] = f2bf(__expf(acc[mi][ni][i] * SCALE));
            }
    } else {
        #pragma unroll
        for (int mi = 0; mi < 4; mi++)
          #pragma unroll
          for (int ni = 0; ni < 4; ni++)
            #pragma unroll
            for (int i = 0; i < 4; i++) {
                int row = gm0 + wm * 64 + mi * 16 + quad * 4 + i;
                int col = gn0 + wn * 64 + ni * 16 + lm - 256;
                Vo[(size_t)row * 512 + col] = f2bf(acc[mi][ni][i]);
            }
    }
}

// ---------------------------------------------------------------------------
// P2a (MFMA): per chunk, one wave: M_c = KE^T(16x64) . V(64x64), lsum = KE^T . 1
// ---------------------------------------------------------------------------
__global__ __launch_bounds__(256, 2) void chunk_sums_mfma(
        const u16* __restrict__ KE, const u16* __restrict__ V,
        float* __restrict__ Mc, float* __restrict__ AB)
{
    struct CLDS { u16 KA[16][72]; u16 VT[64][72]; };
    __shared__ __align__(16) CLDS lds[4];
    const int tid = threadIdx.x, wave = tid >> 6, lane = tid & 63;
    const int lm = lane & 15, quad = lane >> 4;
    const int ch = blockIdx.x * 4 + wave;
    const int bh = ch >> 6, c = ch & 63, b = bh >> 3, h = bh & 7;
    const int t0 = b * T_ + c * 64;
    CLDS& L = lds[wave];

    {
        const u16* kp = KE + (size_t)(t0 + lane) * L_ + h * Lh_;
        v8u k0 = *(const v8u*)kp, k1 = *(const v8u*)(kp + 8);
        #pragma unroll
        for (int l = 0; l < 8; l++) L.KA[l][lane]     = k0[l];
        #pragma unroll
        for (int l = 0; l < 8; l++) L.KA[l + 8][lane] = k1[l];
        const u16* vp = V + (size_t)(t0 + lane) * D_ + h * Dh_;
        #pragma unroll
        for (int seg = 0; seg < 8; ++seg) {
            v8u pv = *(const v8u*)(vp + seg * 8);
            #pragma unroll
            for (int j = 0; j < 8; j++) L.VT[seg * 8 + j][lane] = pv[j];
        }
    }
    __syncthreads();

    v8bf ka[2];
    #pragma unroll
    for (int ki = 0; ki < 2; ki++)
        ka[ki] = *(const v8bf*)&L.KA[lm][ki * 32 + quad * 8];

    v8u onesu;
    #pragma unroll
    for (int j = 0; j < 8; j++) onesu[j] = 0x3F80;
    v8bf ones = __builtin_bit_cast(v8bf, onesu);

    v4f accL = (v4f){0.f, 0.f, 0.f, 0.f};
    accL = __builtin_amdgcn_mfma_f32_16x16x32_bf16(ka[0], ones, accL, 0, 0, 0);
    accL = __builtin_amdgcn_mfma_f32_16x16x32_bf16(ka[1], ones, accL, 0, 0, 0);

    v4f accM[4];
    #pragma unroll
    for (int nd = 0; nd < 4; nd++) accM[nd] = (v4f){0.f, 0.f, 0.f, 0.f};
    #pragma unroll
    for (int nd = 0; nd < 4; nd++)
        #pragma unroll
        for (int ki = 0; ki < 2; ki++) {
            v8bf vb = *(const v8bf*)&L.VT[nd * 16 + lm][ki * 32 + quad * 8];
            accM[nd] = __builtin_amdgcn_mfma_f32_16x16x32_bf16(ka[ki], vb, accM[nd], 0, 0, 0);
        }

    float* mcb = Mc + (size_t)ch * 1024;
    #pragma unroll
    for (int nd = 0; nd < 4; nd++)
        #pragma unroll
        for (int i = 0; i < 4; i++)
            mcb[(quad * 4 + i) * 64 + nd * 16 + lm] = accM[nd][i];
    if (lm == 0) {
        #pragma unroll
        for (int i = 0; i < 4; i++) AB[ch * 16 + quad * 4 + i] = accL[i];
    }
}

// ---------------------------------------------------------------------------
// P2b: exclusive prefix over chunks.  Preload all 64 chunk values as
// INDEPENDENT loads (latency hidden), scan in-register, store as bf16
// (intra consumed f2bf(Mc) anyway -> bit-identical at the MFMA, half traffic).
// 256 blocks x 256 threads.  McB must not alias Mc (type-size change).
// ---------------------------------------------------------------------------
__global__ __launch_bounds__(256) void chunk_prefix(
        const float* __restrict__ Mc, u16* __restrict__ McB,
        float* __restrict__ AB)
{
    const int bh = blockIdx.x >> 2, qq = blockIdx.x & 3;
    const int i = qq * 256 + threadIdx.x;
    const size_t base = (size_t)bh * 64 * 1024 + i;
    float v[64];
    #pragma unroll
    for (int c = 0; c < 64; ++c) v[c] = Mc[base + (size_t)c * 1024];
    float run = 0.f;
    #pragma unroll
    for (int c = 0; c < 64; ++c) {
        McB[base + (size_t)c * 1024] = f2bf(run);
        run += v[c];
    }
    if (qq == 0 && threadIdx.x < 16) {
        const int l = threadIdx.x;
        float a[64];
        #pragma unroll
        for (int c = 0; c < 64; ++c) a[c] = AB[(bh * 64 + c) * 16 + l];
        float r2 = 0.f;
        #pragma unroll
        for (int c = 0; c < 64; ++c) {
            AB[(bh * 64 + c) * 16 + l] = r2;
            r2 += a[c];
        }
    }
}

// ---------------------------------------------------------------------------
// P3 (MFMA): alpha = AB + tril.ke; qs = QS/alpha (QS pre-softmaxed in gemm0);
// P = QS.KE^T (masked); Y = QS.S_c + P.V
// ---------------------------------------------------------------------------
__global__ __launch_bounds__(256, 2) void intra_mfma(
        const float* __restrict__ QS, const u16* __restrict__ KE,
        const u16* __restrict__ V, const u16* __restrict__ McB,
        const float* __restrict__ AB, u16* __restrict__ Y)
{
    struct ILDS {
        union {
            struct { u16 KA[16][72]; u16 Sc[16][72]; u16 qs[64][40]; } s;
            u16 p[64][72];
        } r;
        u16 VT[64][72];
    };
    __shared__ __align__(16) ILDS lds[4];
    const int tid = threadIdx.x, wave = tid >> 6, lane = tid & 63;
    const int lm = lane & 15, quad = lane >> 4;
    const int ch = blockIdx.x * 4 + wave;
    const int bh = ch >> 6, c = ch & 63, b = bh >> 3, h = bh & 7;
    const int t0 = b * T_ + c * 64;
    ILDS& L = lds[wave];

    {
        const u16* kp = KE + (size_t)(t0 + lane) * L_ + h * Lh_;
        v8u k0 = *(const v8u*)kp, k1 = *(const v8u*)(kp + 8);
        #pragma unroll
        for (int l = 0; l < 8; l++) L.r.s.KA[l][lane]     = k0[l];
        #pragma unroll
        for (int l = 0; l < 8; l++) L.r.s.KA[l + 8][lane] = k1[l];
        const u16* vp = V + (size_t)(t0 + lane) * D_ + h * Dh_;
        #pragma unroll
        for (int seg = 0; seg < 8; ++seg) {
            v8u pv = *(const v8u*)(vp + seg * 8);
            #pragma unroll
            for (int j = 0; j < 8; j++) L.VT[seg * 8 + j][lane] = pv[j];
        }
        const u16* mcb = McB + (size_t)ch * 1024;
        #pragma unroll
        for (int l = 0; l < 16; l++)
            L.r.s.Sc[l][lane] = mcb[l * 64 + lane];
        v8u z8;
        #pragma unroll
        for (int j = 0; j < 8; j++) z8[j] = 0;
        *(v8u*)&L.r.s.qs[lane][16] = z8;
        *(v8u*)&L.r.s.qs[lane][24] = z8;
    }
    const float ab = AB[ch * 16 + lm];
    __syncthreads();

    v4f acc_a[4];
    #pragma unroll
    for (int mi = 0; mi < 4; mi++) acc_a[mi] = (v4f){ab, ab, ab, ab};
    #pragma unroll
    for (int mi = 0; mi < 4; mi++)
        #pragma unroll
        for (int ki = 0; ki < 2; ki++) {
            if (ki == 1 && mi < 2) continue;
            v8u ta;
            #pragma unroll
            for (int j = 0; j < 8; j++)
                ta[j] = (ki * 32 + quad * 8 + j <= mi * 16 + lm) ? (u16)0x3F80 : (u16)0;
            v8bf kb = *(const v8bf*)&L.r.s.KA[lm][ki * 32 + quad * 8];
            acc_a[mi] = __builtin_amdgcn_mfma_f32_16x16x32_bf16(
                            __builtin_bit_cast(v8bf, ta), kb, acc_a[mi], 0, 0, 0);
        }

    #pragma unroll
    for (int mi = 0; mi < 4; mi++)
        #pragma unroll
        for (int i = 0; i < 4; i++) {
            int t = mi * 16 + quad * 4 + i;
            float qs = QS[(size_t)(t0 + t) * L_ + h * Lh_ + lm];
            L.r.s.qs[t][lm] = f2bf(qs / acc_a[mi][i]);
        }
    __syncthreads();

    v8bf aq[4];
    #pragma unroll
    for (int mi = 0; mi < 4; mi++)
        aq[mi] = *(const v8bf*)&L.r.s.qs[mi * 16 + lm][quad * 8];

    v4f accP[4][4], accY[4][4];
    #pragma unroll
    for (int mi = 0; mi < 4; mi++)
        #pragma unroll
        for (int ni = 0; ni < 4; ni++) {
            accP[mi][ni] = (v4f){0.f, 0.f, 0.f, 0.f};
            accY[mi][ni] = (v4f){0.f, 0.f, 0.f, 0.f};
        }

    #pragma unroll
    for (int ni = 0; ni < 4; ni++) {
        v8u kbu;
        #pragma unroll
        for (int j = 0; j < 8; j++) kbu[j] = 0;
        if (quad < 2) {
            #pragma unroll
            for (int j = 0; j < 8; j++)
                kbu[j] = L.r.s.KA[quad * 8 + j][ni * 16 + lm];
        }
        v8bf kbf = __builtin_bit_cast(v8bf, kbu);
        #pragma unroll
        for (int mi = ni; mi < 4; mi++)
            accP[mi][ni] = __builtin_amdgcn_mfma_f32_16x16x32_bf16(
                               aq[mi], kbf, accP[mi][ni], 0, 0, 0);
    }
    #pragma unroll
    for (int nd = 0; nd < 4; nd++) {
        v8u scu;
        #pragma unroll
        for (int j = 0; j < 8; j++) scu[j] = 0;
        if (quad < 2) {
            #pragma unroll
            for (int j = 0; j < 8; j++)
                scu[j] = L.r.s.Sc[quad * 8 + j][nd * 16 + lm];
        }
        v8bf scf = __builtin_bit_cast(v8bf, scu);
        #pragma unroll
        for (int mi = 0; mi < 4; mi++)
            accY[mi][nd] = __builtin_amdgcn_mfma_f32_16x16x32_bf16(
                               aq[mi], scf, accY[mi][nd], 0, 0, 0);
    }
    __syncthreads();

    #pragma unroll
    for (int mi = 0; mi < 4; mi++)
        #pragma unroll
        for (int ni = 0; ni < 4; ni++)
            #pragma unroll
            for (int i = 0; i < 4; i++) {
                int t = mi * 16 + quad * 4 + i, tp = ni * 16 + lm;
                float pv = (ni < mi) ? accP[mi][ni][i]
                          : (ni == mi ? ((tp <= t) ? accP[mi][ni][i] : 0.f) : 0.f);
                L.r.p[t][tp] = f2bf(pv);
            }
    __syncthreads();

    v8bf vb[4][2];
    #pragma unroll
    for (int nd = 0; nd < 4; nd++)
        #pragma unroll
        for (int ki = 0; ki < 2; ki++)
            vb[nd][ki] = *(const v8bf*)&L.VT[nd * 16 + lm][ki * 32 + quad * 8];
    #pragma unroll
    for (int mi = 0; mi < 4; mi++)
        #pragma unroll
        for (int ki = 0; ki < 2; ki++) {
            if (ki == 1 && mi < 2) continue;
            v8bf pa = *(const v8bf*)&L.r.p[mi * 16 + lm][ki * 32 + quad * 8];
            #pragma unroll
            for (int nd = 0; nd < 4; nd++)
                accY[mi][nd] = __builtin_amdgcn_mfma_f32_16x16x32_bf16(
                                   pa, vb[nd][ki], accY[mi][nd], 0, 0, 0);
        }

    #pragma unroll
    for (int mi = 0; mi < 4; mi++)
        #pragma unroll
        for (int nd = 0; nd < 4; nd++)
            #pragma unroll
            for (int i = 0; i < 4; i++) {
                int t = mi * 16 + quad * 4 + i;
                Y[(((size_t)(c * 64 + t)) * 64 + bh) * 64 + nd * 16 + lm] =
                    f2bf(accY[mi][nd][i]);
            }
}

// ---------------------------------------------------------------------------
// P4: Z = Y^T :  Y (262144 x 64) -> Z (64 x 262144).  Both sides coalesced:
// write pass p covers 8 Z-rows; 8 lanes cover 128B contiguous per store.
// ---------------------------------------------------------------------------
__global__ __launch_bounds__(64) void transpose_Y(
        const u16* __restrict__ Y, u16* __restrict__ Z)
{
    __shared__ __align__(16) u16 tile[64][72];
    const int g = blockIdx.x, t = threadIdx.x;
    const u16* yp = Y + (size_t)(g * 64 + t) * 64;
    #pragma unroll
    for (int seg = 0; seg < 8; ++seg)
        *(v8u*)&tile[t][seg * 8] = *(const v8u*)(yp + seg * 8);
    __syncthreads();
    const int cl = t & 7, dq = t >> 3;
    #pragma unroll
    for (int p = 0; p < 8; ++p) {
        const int dh = p * 8 + dq;
        v8u pk;
        #pragma unroll
        for (int j = 0; j < 8; j++) pk[j] = tile[cl * 8 + j][dh];
        *(v8u*)&Z[(size_t)dh * 262144 + (size_t)g * 64 + cl * 8] = pk;
    }
}

// ---------------------------------------------------------------------------
extern "C" void kernel_launch(void* const* d_in, const int* in_sizes, int n_in,
                              void* d_out, int out_size, void* d_ws, size_t ws_size,
                              hipStream_t stream)
{
    (void)in_sizes; (void)n_in; (void)out_size; (void)ws_size;
    const float* X  = (const float*)d_in[0];
    const float* Wk = (const float*)d_in[1];   // dict order: X, Wk, Wq, Wv, o_proj
    const float* Wq = (const float*)d_in[2];
    const float* Wv = (const float*)d_in[3];
    const float* Wo = (const float*)d_in[4];
    float* Out = (float*)d_out;

    char* p = (char*)d_ws;
    auto alloc = [&](size_t bytes) { char* r = p; p += (bytes + 255) & ~(size_t)255; return r; };
    u16*   Xb = (u16*)  alloc((size_t)M_ * 512 * 2);
    u16*   WT = (u16*)  alloc((size_t)768 * 512 * 2);
    u16*   OT = (u16*)  alloc((size_t)512 * 512 * 2);
    u16*   V  = (u16*)  alloc((size_t)M_ * 512 * 2);
    float* Mc = (float*)alloc((size_t)4096 * 1024 * 4);   // 16.78 MB
    float* AB = (float*)alloc((size_t)4096 * 16 * 4);
    float* Q  = (float*)alloc((size_t)M_ * 128 * 4);      // QS (softmaxed), fp32
    u16*   KE = (u16*)  alloc((size_t)M_ * 128 * 2);
    u16*   Y  = (u16*)  alloc((size_t)M_ * 512 * 2);
    u16*   Z  = (u16*)Mc;   // alias: Mc+AB+Q (33.8MB) dead after intra; Z needs 33.5MB
    u16*   McB = (u16*)Xb;  // alias: Xb dead after gemm0; bf16 prefix (8.39MB)

    prep<<<8832, 256, 0, stream>>>(X, Wq, Wk, Wv, Wo, Xb, WT, OT);

    gemm_mfma<0><<<dim3(256, 6), 256, 0, stream>>>(Xb, WT, Q, KE, V, nullptr);
    chunk_sums_mfma<<<1024, 256, 0, stream>>>(KE, V, Mc, AB);
    chunk_prefix   <<<256,  256, 0, stream>>>(Mc, McB, AB);
    intra_mfma     <<<1024, 256, 0, stream>>>(Q, KE, V, McB, AB, Y);
    transpose_Y    <<<4096, 64,  0, stream>>>(Y, Z);
    gemm_mfma<1><<<dim3(256, 4), 256, 0, stream>>>(Z, OT, nullptr, nullptr, nullptr, Out);
}

// Round 3
// 254.601 us; speedup vs baseline: 1.0138x; 1.0138x over previous
//
#include <hip/hip_runtime.h>
#include <hip/hip_bf16.h>

#define B_ 8
#define T_ 4096
#define D_ 512
#define L_ 128
#define H_ 8
#define Dh_ 64
#define Lh_ 16
#define M_ (B_*T_)          // 32768 rows
#define SCALE 0.125f        // rsqrt(Dh)

typedef __bf16 v8bf __attribute__((ext_vector_type(8)));
typedef float  v4f  __attribute__((ext_vector_type(4)));
typedef unsigned short u16;
typedef u16 v8u __attribute__((ext_vector_type(8)));

__device__ __forceinline__ float b2f(u16 h){
    unsigned int u = ((unsigned int)h) << 16;
    return __builtin_bit_cast(float, u);
}
__device__ __forceinline__ u16 f2bf(float f){
    unsigned int u = __builtin_bit_cast(unsigned int, f);
    u += 0x7FFFu + ((u >> 16) & 1u);   // RNE
    return (u16)(u >> 16);
}

// async global->LDS, 16B per lane; lds dest = wave-uniform base + lane*16
__device__ __forceinline__ void gload16(const u16* g, u16* l) {
    __builtin_amdgcn_global_load_lds(
        (const __attribute__((address_space(1))) unsigned int*)(g),
        (__attribute__((address_space(3))) unsigned int*)(l), 16, 0, 0);
}

// ---------------------------------------------------------------------------
// prep: one launch = X fp32->bf16 convert (blocks 0..8191) + 4 weight
// transposes fp32(rows x cols) -> bf16 (cols x rows) (blocks 8192..8831)
// ---------------------------------------------------------------------------
__global__ __launch_bounds__(256) void prep(
        const float* __restrict__ X,  const float* __restrict__ Wq,
        const float* __restrict__ Wk, const float* __restrict__ Wv,
        const float* __restrict__ Wo,
        u16* __restrict__ Xb, u16* __restrict__ WT, u16* __restrict__ OT)
{
    int bid = blockIdx.x;
    if (bid < 8192) {   // X convert: 8 elems / thread
        const size_t i = (size_t)bid * 256 + threadIdx.x;
        const float4* s = (const float4*)X + i * 2;
        float4 a = s[0], b = s[1];
        v8u o;
        o[0] = f2bf(a.x); o[1] = f2bf(a.y); o[2] = f2bf(a.z); o[3] = f2bf(a.w);
        o[4] = f2bf(b.x); o[5] = f2bf(b.y); o[6] = f2bf(b.z); o[7] = f2bf(b.w);
        *((v8u*)Xb + i) = o;
        return;
    }
    bid -= 8192;
    const float* src; u16* dst; int cols, bx, by;
    if (bid < 64)       { src = Wq; dst = WT;             cols = 128; bx = bid & 3;  by = bid >> 2; }
    else if (bid < 128) { src = Wk; dst = WT + 128 * 512; cols = 128; bid -= 64;  bx = bid & 3;  by = bid >> 2; }
    else if (bid < 384) { src = Wv; dst = WT + 256 * 512; cols = 512; bid -= 128; bx = bid & 15; by = bid >> 4; }
    else                { src = Wo; dst = OT;             cols = 512; bid -= 384; bx = bid & 15; by = bid >> 4; }
    __shared__ u16 tile[32][33];
    const int tx = threadIdx.x & 31, ty = threadIdx.x >> 5;
    const int c0 = bx * 32, r0 = by * 32;
    #pragma unroll
    for (int i = 0; i < 32; i += 8)
        tile[ty + i][tx] = f2bf(src[(size_t)(r0 + ty + i) * cols + c0 + tx]);
    __syncthreads();
    #pragma unroll
    for (int i = 0; i < 32; i += 8)
        dst[(size_t)(c0 + ty + i) * 512 + r0 + tx] = tile[tx][ty + i];
}

// ---------------------------------------------------------------------------
// P1/P5: MFMA bf16 GEMM, m97-style single-buffer (round-1 structure: best
// measured).  BK=64, global_load_lds width=16, XOR granule swizzle.
// 1D grid + XCD-aware swizzle (T1): xcd=bid&7 owns 32 contiguous A-panels,
// sweeping the NY column-blocks fastest, so the NY blocks sharing an A-panel
// run adjacently on the same XCD -> A-panel served from that XCD's L2.
// MODE 0 (NY=6): write QS=softmax(Q*s)(f32) / KE=exp(K*s)(bf16) / V(bf16).
// MODE 1 (NY=4): fp32 Out.
// ---------------------------------------------------------------------------
template<int MODE, int NY>
__global__ __launch_bounds__(256) void gemm_mfma(
        const u16* __restrict__ A, const u16* __restrict__ Bt,
        float* __restrict__ Qo, u16* __restrict__ KEo,
        u16* __restrict__ Vo, float* __restrict__ OutF)
{
    __shared__ __align__(16) u16 As[128 * 64];   // row*64 + (g^(row&7))*8
    __shared__ __align__(16) u16 Bs[128 * 64];
    const int tid  = threadIdx.x;
    const int wave = tid >> 6, lane = tid & 63;
    const int wm = wave >> 1, wn = wave & 1;     // 2x2 waves, 64x64 each
    const int lm = lane & 15, quad = lane >> 4;

    // XCD-aware swizzle: grid = 256*NY blocks = 8 XCDs * 32 panels * NY cols
    const int bid = blockIdx.x;
    const int xcd = bid & 7, idx = bid >> 3;
    const int bx  = xcd * 32 + idx / NY;         // A-panel (row-block)
    const int by  = idx % NY;                    // column-block
    const int gm0 = bx * 128, gn0 = by * 128;

    const int srow0 = wave * 32 + (lane >> 3);   // staging row, + r*8
    const int sg    = lane & 7;                  // staging granule position

    v4f acc[4][4];
    #pragma unroll
    for (int i = 0; i < 4; i++)
        #pragma unroll
        for (int j = 0; j < 4; j++)
            acc[i][j] = (v4f){0.f, 0.f, 0.f, 0.f};

    for (int kt = 0; kt < 8; ++kt) {
        const int k0 = kt * 64;
        #pragma unroll
        for (int r = 0; r < 4; ++r) {
            const int row = srow0 + r * 8;
            const int col = ((sg ^ (row & 7)) << 3) + k0;   // source k-granule
            gload16(&A [(size_t)(gm0 + row) * 512 + col], &As[(wave * 4 + r) * 512]);
            gload16(&Bt[(size_t)(gn0 + row) * 512 + col], &Bs[(wave * 4 + r) * 512]);
        }
        __syncthreads();
        v8bf af[2][4], bfr[2][4];
        #pragma unroll
        for (int ks = 0; ks < 2; ks++)
            #pragma unroll
            for (int mi = 0; mi < 4; mi++) {
                const int g  = ks * 4 + quad;
                const int ra = wm * 64 + mi * 16 + lm;
                const int rb = wn * 64 + mi * 16 + lm;
                af [ks][mi] = *(const v8bf*)&As[ra * 64 + ((g ^ (ra & 7)) << 3)];
                bfr[ks][mi] = *(const v8bf*)&Bs[rb * 64 + ((g ^ (rb & 7)) << 3)];
            }
        #pragma unroll
        for (int ks = 0; ks < 2; ks++)
            #pragma unroll
            for (int mi = 0; mi < 4; mi++)
                #pragma unroll
                for (int ni = 0; ni < 4; ni++)
                    acc[mi][ni] = __builtin_amdgcn_mfma_f32_16x16x32_bf16(
                                      af[ks][mi], bfr[ks][ni], acc[mi][ni], 0, 0, 0);
        __syncthreads();
    }

    if (MODE == 1) {
        #pragma unroll
        for (int mi = 0; mi < 4; mi++)
          #pragma unroll
          for (int ni = 0; ni < 4; ni++)
            #pragma unroll
            for (int i = 0; i < 4; i++) {
                int row = gm0 + wm * 64 + mi * 16 + quad * 4 + i;
                int col = gn0 + wn * 64 + ni * 16 + lm;
                OutF[(size_t)row * 512 + col] = acc[mi][ni][i];
            }
    } else if (gn0 == 0) {
        // Q block: fold the row-softmax here. For fixed (mi,ni,i) the 16 lanes
        // lm hold exactly one head's Lh=16 values -> 16-lane shfl reduce.
        #pragma unroll
        for (int mi = 0; mi < 4; mi++)
          #pragma unroll
          for (int ni = 0; ni < 4; ni++)
            #pragma unroll
            for (int i = 0; i < 4; i++) {
                int row = gm0 + wm * 64 + mi * 16 + quad * 4 + i;
                int col = wn * 64 + ni * 16 + lm;
                float qv = acc[mi][ni][i] * SCALE;
                float m = qv;
                #pragma unroll
                for (int off = 1; off < 16; off <<= 1) m = fmaxf(m, __shfl_xor(m, off));
                float e = __expf(qv - m);
                float s = e;
                #pragma unroll
                for (int off = 1; off < 16; off <<= 1) s += __shfl_xor(s, off);
                Qo[(size_t)row * 128 + col] = e / s;
            }
    } else if (gn0 == 128) {
        #pragma unroll
        for (int mi = 0; mi < 4; mi++)
          #pragma unroll
          for (int ni = 0; ni < 4; ni++)
            #pragma unroll
            for (int i = 0; i < 4; i++) {
                int row = gm0 + wm * 64 + mi * 16 + quad * 4 + i;
                int col = wn * 64 + ni * 16 + lm;
                KEo[(size_t)row * 128 + col] = f2bf(__expf(acc[mi][ni][i] * SCALE));
            }
    } else {
        #pragma unroll
        for (int mi = 0; mi < 4; mi++)
          #pragma unroll
          for (int ni = 0; ni < 4; ni++)
            #pragma unroll
            for (int i = 0; i < 4; i++) {
                int row = gm0 + wm * 64 + mi * 16 + quad * 4 + i;
                int col = gn0 + wn * 64 + ni * 16 + lm - 256;
                Vo[(size_t)row * 512 + col] = f2bf(acc[mi][ni][i]);
            }
    }
}

// ---------------------------------------------------------------------------
// P2a (MFMA): per chunk, one wave: M_c = KE^T(16x64) . V(64x64), lsum = KE^T . 1
// ---------------------------------------------------------------------------
__global__ __launch_bounds__(256, 2) void chunk_sums_mfma(
        const u16* __restrict__ KE, const u16* __restrict__ V,
        float* __restrict__ Mc, float* __restrict__ AB)
{
    struct CLDS { u16 KA[16][72]; u16 VT[64][72]; };
    __shared__ __align__(16) CLDS lds[4];
    const int tid = threadIdx.x, wave = tid >> 6, lane = tid & 63;
    const int lm = lane & 15, quad = lane >> 4;
    const int ch = blockIdx.x * 4 + wave;
    const int bh = ch >> 6, c = ch & 63, b = bh >> 3, h = bh & 7;
    const int t0 = b * T_ + c * 64;
    CLDS& L = lds[wave];

    {
        const u16* kp = KE + (size_t)(t0 + lane) * L_ + h * Lh_;
        v8u k0 = *(const v8u*)kp, k1 = *(const v8u*)(kp + 8);
        #pragma unroll
        for (int l = 0; l < 8; l++) L.KA[l][lane]     = k0[l];
        #pragma unroll
        for (int l = 0; l < 8; l++) L.KA[l + 8][lane] = k1[l];
        const u16* vp = V + (size_t)(t0 + lane) * D_ + h * Dh_;
        #pragma unroll
        for (int seg = 0; seg < 8; ++seg) {
            v8u pv = *(const v8u*)(vp + seg * 8);
            #pragma unroll
            for (int j = 0; j < 8; j++) L.VT[seg * 8 + j][lane] = pv[j];
        }
    }
    __syncthreads();

    v8bf ka[2];
    #pragma unroll
    for (int ki = 0; ki < 2; ki++)
        ka[ki] = *(const v8bf*)&L.KA[lm][ki * 32 + quad * 8];

    v8u onesu;
    #pragma unroll
    for (int j = 0; j < 8; j++) onesu[j] = 0x3F80;
    v8bf ones = __builtin_bit_cast(v8bf, onesu);

    v4f accL = (v4f){0.f, 0.f, 0.f, 0.f};
    accL = __builtin_amdgcn_mfma_f32_16x16x32_bf16(ka[0], ones, accL, 0, 0, 0);
    accL = __builtin_amdgcn_mfma_f32_16x16x32_bf16(ka[1], ones, accL, 0, 0, 0);

    v4f accM[4];
    #pragma unroll
    for (int nd = 0; nd < 4; nd++) accM[nd] = (v4f){0.f, 0.f, 0.f, 0.f};
    #pragma unroll
    for (int nd = 0; nd < 4; nd++)
        #pragma unroll
        for (int ki = 0; ki < 2; ki++) {
            v8bf vb = *(const v8bf*)&L.VT[nd * 16 + lm][ki * 32 + quad * 8];
            accM[nd] = __builtin_amdgcn_mfma_f32_16x16x32_bf16(ka[ki], vb, accM[nd], 0, 0, 0);
        }

    float* mcb = Mc + (size_t)ch * 1024;
    #pragma unroll
    for (int nd = 0; nd < 4; nd++)
        #pragma unroll
        for (int i = 0; i < 4; i++)
            mcb[(quad * 4 + i) * 64 + nd * 16 + lm] = accM[nd][i];
    if (lm == 0) {
        #pragma unroll
        for (int i = 0; i < 4; i++) AB[ch * 16 + quad * 4 + i] = accL[i];
    }
}

// ---------------------------------------------------------------------------
// P2b: exclusive prefix over chunks.  Preload all 64 chunk values as
// INDEPENDENT loads (latency hidden), scan in-register, store as bf16
// (intra consumed f2bf(Mc) anyway -> bit-identical at the MFMA, half traffic).
// 256 blocks x 256 threads.  McB must not alias Mc (type-size change).
// ---------------------------------------------------------------------------
__global__ __launch_bounds__(256) void chunk_prefix(
        const float* __restrict__ Mc, u16* __restrict__ McB,
        float* __restrict__ AB)
{
    const int bh = blockIdx.x >> 2, qq = blockIdx.x & 3;
    const int i = qq * 256 + threadIdx.x;
    const size_t base = (size_t)bh * 64 * 1024 + i;
    float v[64];
    #pragma unroll
    for (int c = 0; c < 64; ++c) v[c] = Mc[base + (size_t)c * 1024];
    float run = 0.f;
    #pragma unroll
    for (int c = 0; c < 64; ++c) {
        McB[base + (size_t)c * 1024] = f2bf(run);
        run += v[c];
    }
    if (qq == 0 && threadIdx.x < 16) {
        const int l = threadIdx.x;
        float a[64];
        #pragma unroll
        for (int c = 0; c < 64; ++c) a[c] = AB[(bh * 64 + c) * 16 + l];
        float r2 = 0.f;
        #pragma unroll
        for (int c = 0; c < 64; ++c) {
            AB[(bh * 64 + c) * 16 + l] = r2;
            r2 += a[c];
        }
    }
}

// ---------------------------------------------------------------------------
// P3 (MFMA): alpha = AB + tril.ke; qs = QS/alpha (QS pre-softmaxed in gemm0);
// P = QS.KE^T (masked); Y = QS.S_c + P.V
// ---------------------------------------------------------------------------
__global__ __launch_bounds__(256, 2) void intra_mfma(
        const float* __restrict__ QS, const u16* __restrict__ KE,
        const u16* __restrict__ V, const u16* __restrict__ McB,
        const float* __restrict__ AB, u16* __restrict__ Y)
{
    struct ILDS {
        union {
            struct { u16 KA[16][72]; u16 Sc[16][72]; u16 qs[64][40]; } s;
            u16 p[64][72];
        } r;
        u16 VT[64][72];
    };
    __shared__ __align__(16) ILDS lds[4];
    const int tid = threadIdx.x, wave = tid >> 6, lane = tid & 63;
    const int lm = lane & 15, quad = lane >> 4;
    const int ch = blockIdx.x * 4 + wave;
    const int bh = ch >> 6, c = ch & 63, b = bh >> 3, h = bh & 7;
    const int t0 = b * T_ + c * 64;
    ILDS& L = lds[wave];

    {
        const u16* kp = KE + (size_t)(t0 + lane) * L_ + h * Lh_;
        v8u k0 = *(const v8u*)kp, k1 = *(const v8u*)(kp + 8);
        #pragma unroll
        for (int l = 0; l < 8; l++) L.r.s.KA[l][lane]     = k0[l];
        #pragma unroll
        for (int l = 0; l < 8; l++) L.r.s.KA[l + 8][lane] = k1[l];
        const u16* vp = V + (size_t)(t0 + lane) * D_ + h * Dh_;
        #pragma unroll
        for (int seg = 0; seg < 8; ++seg) {
            v8u pv = *(const v8u*)(vp + seg * 8);
            #pragma unroll
            for (int j = 0; j < 8; j++) L.VT[seg * 8 + j][lane] = pv[j];
        }
        const u16* mcb = McB + (size_t)ch * 1024;
        #pragma unroll
        for (int l = 0; l < 16; l++)
            L.r.s.Sc[l][lane] = mcb[l * 64 + lane];
        v8u z8;
        #pragma unroll
        for (int j = 0; j < 8; j++) z8[j] = 0;
        *(v8u*)&L.r.s.qs[lane][16] = z8;
        *(v8u*)&L.r.s.qs[lane][24] = z8;
    }
    const float ab = AB[ch * 16 + lm];
    __syncthreads();

    v4f acc_a[4];
    #pragma unroll
    for (int mi = 0; mi < 4; mi++) acc_a[mi] = (v4f){ab, ab, ab, ab};
    #pragma unroll
    for (int mi = 0; mi < 4; mi++)
        #pragma unroll
        for (int ki = 0; ki < 2; ki++) {
            if (ki == 1 && mi < 2) continue;
            v8u ta;
            #pragma unroll
            for (int j = 0; j < 8; j++)
                ta[j] = (ki * 32 + quad * 8 + j <= mi * 16 + lm) ? (u16)0x3F80 : (u16)0;
            v8bf kb = *(const v8bf*)&L.r.s.KA[lm][ki * 32 + quad * 8];
            acc_a[mi] = __builtin_amdgcn_mfma_f32_16x16x32_bf16(
                            __builtin_bit_cast(v8bf, ta), kb, acc_a[mi], 0, 0, 0);
        }

    #pragma unroll
    for (int mi = 0; mi < 4; mi++)
        #pragma unroll
        for (int i = 0; i < 4; i++) {
            int t = mi * 16 + quad * 4 + i;
            float qs = QS[(size_t)(t0 + t) * L_ + h * Lh_ + lm];
            L.r.s.qs[t][lm] = f2bf(qs / acc_a[mi][i]);
        }
    __syncthreads();

    v8bf aq[4];
    #pragma unroll
    for (int mi = 0; mi < 4; mi++)
        aq[mi] = *(const v8bf*)&L.r.s.qs[mi * 16 + lm][quad * 8];

    v4f accP[4][4], accY[4][4];
    #pragma unroll
    for (int mi = 0; mi < 4; mi++)
        #pragma unroll
        for (int ni = 0; ni < 4; ni++) {
            accP[mi][ni] = (v4f){0.f, 0.f, 0.f, 0.f};
            accY[mi][ni] = (v4f){0.f, 0.f, 0.f, 0.f};
        }

    #pragma unroll
    for (int ni = 0; ni < 4; ni++) {
        v8u kbu;
        #pragma unroll
        for (int j = 0; j < 8; j++) kbu[j] = 0;
        if (quad < 2) {
            #pragma unroll
            for (int j = 0; j < 8; j++)
                kbu[j] = L.r.s.KA[quad * 8 + j][ni * 16 + lm];
        }
        v8bf kbf = __builtin_bit_cast(v8bf, kbu);
        #pragma unroll
        for (int mi = ni; mi < 4; mi++)
            accP[mi][ni] = __builtin_amdgcn_mfma_f32_16x16x32_bf16(
                               aq[mi], kbf, accP[mi][ni], 0, 0, 0);
    }
    #pragma unroll
    for (int nd = 0; nd < 4; nd++) {
        v8u scu;
        #pragma unroll
        for (int j = 0; j < 8; j++) scu[j] = 0;
        if (quad < 2) {
            #pragma unroll
            for (int j = 0; j < 8; j++)
                scu[j] = L.r.s.Sc[quad * 8 + j][nd * 16 + lm];
        }
        v8bf scf = __builtin_bit_cast(v8bf, scu);
        #pragma unroll
        for (int mi = 0; mi < 4; mi++)
            accY[mi][nd] = __builtin_amdgcn_mfma_f32_16x16x32_bf16(
                               aq[mi], scf, accY[mi][nd], 0, 0, 0);
    }
    __syncthreads();

    #pragma unroll
    for (int mi = 0; mi < 4; mi++)
        #pragma unroll
        for (int ni = 0; ni < 4; ni++)
            #pragma unroll
            for (int i = 0; i < 4; i++) {
                int t = mi * 16 + quad * 4 + i, tp = ni * 16 + lm;
                float pv = (ni < mi) ? accP[mi][ni][i]
                          : (ni == mi ? ((tp <= t) ? accP[mi][ni][i] : 0.f) : 0.f);
                L.r.p[t][tp] = f2bf(pv);
            }
    __syncthreads();

    v8bf vb[4][2];
    #pragma unroll
    for (int nd = 0; nd < 4; nd++)
        #pragma unroll
        for (int ki = 0; ki < 2; ki++)
            vb[nd][ki] = *(const v8bf*)&L.VT[nd * 16 + lm][ki * 32 + quad * 8];
    #pragma unroll
    for (int mi = 0; mi < 4; mi++)
        #pragma unroll
        for (int ki = 0; ki < 2; ki++) {
            if (ki == 1 && mi < 2) continue;
            v8bf pa = *(const v8bf*)&L.r.p[mi * 16 + lm][ki * 32 + quad * 8];
            #pragma unroll
            for (int nd = 0; nd < 4; nd++)
                accY[mi][nd] = __builtin_amdgcn_mfma_f32_16x16x32_bf16(
                                   pa, vb[nd][ki], accY[mi][nd], 0, 0, 0);
        }

    #pragma unroll
    for (int mi = 0; mi < 4; mi++)
        #pragma unroll
        for (int nd = 0; nd < 4; nd++)
            #pragma unroll
            for (int i = 0; i < 4; i++) {
                int t = mi * 16 + quad * 4 + i;
                Y[(((size_t)(c * 64 + t)) * 64 + bh) * 64 + nd * 16 + lm] =
                    f2bf(accY[mi][nd][i]);
            }
}

// ---------------------------------------------------------------------------
// P4: Z = Y^T :  Y (262144 x 64) -> Z (64 x 262144).  Both sides coalesced:
// write pass p covers 8 Z-rows; 8 lanes cover 128B contiguous per store.
// ---------------------------------------------------------------------------
__global__ __launch_bounds__(64) void transpose_Y(
        const u16* __restrict__ Y, u16* __restrict__ Z)
{
    __shared__ __align__(16) u16 tile[64][72];
    const int g = blockIdx.x, t = threadIdx.x;
    const u16* yp = Y + (size_t)(g * 64 + t) * 64;
    #pragma unroll
    for (int seg = 0; seg < 8; ++seg)
        *(v8u*)&tile[t][seg * 8] = *(const v8u*)(yp + seg * 8);
    __syncthreads();
    const int cl = t & 7, dq = t >> 3;
    #pragma unroll
    for (int p = 0; p < 8; ++p) {
        const int dh = p * 8 + dq;
        v8u pk;
        #pragma unroll
        for (int j = 0; j < 8; j++) pk[j] = tile[cl * 8 + j][dh];
        *(v8u*)&Z[(size_t)dh * 262144 + (size_t)g * 64 + cl * 8] = pk;
    }
}

// ---------------------------------------------------------------------------
extern "C" void kernel_launch(void* const* d_in, const int* in_sizes, int n_in,
                              void* d_out, int out_size, void* d_ws, size_t ws_size,
                              hipStream_t stream)
{
    (void)in_sizes; (void)n_in; (void)out_size; (void)ws_size;
    const float* X  = (const float*)d_in[0];
    const float* Wk = (const float*)d_in[1];   // dict order: X, Wk, Wq, Wv, o_proj
    const float* Wq = (const float*)d_in[2];
    const float* Wv = (const float*)d_in[3];
    const float* Wo = (const float*)d_in[4];
    float* Out = (float*)d_out;

    char* p = (char*)d_ws;
    auto alloc = [&](size_t bytes) { char* r = p; p += (bytes + 255) & ~(size_t)255; return r; };
    u16*   Xb = (u16*)  alloc((size_t)M_ * 512 * 2);
    u16*   WT = (u16*)  alloc((size_t)768 * 512 * 2);
    u16*   OT = (u16*)  alloc((size_t)512 * 512 * 2);
    u16*   V  = (u16*)  alloc((size_t)M_ * 512 * 2);
    float* Mc = (float*)alloc((size_t)4096 * 1024 * 4);   // 16.78 MB
    float* AB = (float*)alloc((size_t)4096 * 16 * 4);
    float* Q  = (float*)alloc((size_t)M_ * 128 * 4);      // QS (softmaxed), fp32
    u16*   KE = (u16*)  alloc((size_t)M_ * 128 * 2);
    u16*   Y  = (u16*)  alloc((size_t)M_ * 512 * 2);
    u16*   Z  = (u16*)Mc;   // alias: Mc+AB+Q (33.8MB) dead after intra; Z needs 33.5MB
    u16*   McB = (u16*)Xb;  // alias: Xb dead after gemm0; bf16 prefix (8.39MB)

    prep<<<8832, 256, 0, stream>>>(X, Wq, Wk, Wv, Wo, Xb, WT, OT);

    gemm_mfma<0, 6><<<1536, 256, 0, stream>>>(Xb, WT, Q, KE, V, nullptr);
    chunk_sums_mfma<<<1024, 256, 0, stream>>>(KE, V, Mc, AB);
    chunk_prefix   <<<256,  256, 0, stream>>>(Mc, McB, AB);
    intra_mfma     <<<1024, 256, 0, stream>>>(Q, KE, V, McB, AB, Y);
    transpose_Y    <<<4096, 64,  0, stream>>>(Y, Z);
    gemm_mfma<1, 4><<<1024, 256, 0, stream>>>(Z, OT, nullptr, nullptr, nullptr, Out);
}

// Round 4
// 248.462 us; speedup vs baseline: 1.0388x; 1.0247x over previous
//
#include <hip/hip_runtime.h>
#include <hip/hip_bf16.h>

#define B_ 8
#define T_ 4096
#define D_ 512
#define L_ 128
#define H_ 8
#define Dh_ 64
#define Lh_ 16
#define M_ (B_*T_)          // 32768 rows
#define SCALE 0.125f        // rsqrt(Dh)

typedef __bf16 v8bf __attribute__((ext_vector_type(8)));
typedef float  v4f  __attribute__((ext_vector_type(4)));
typedef unsigned short u16;
typedef u16 v8u __attribute__((ext_vector_type(8)));

__device__ __forceinline__ float b2f(u16 h){
    unsigned int u = ((unsigned int)h) << 16;
    return __builtin_bit_cast(float, u);
}
__device__ __forceinline__ u16 f2bf(float f){
    unsigned int u = __builtin_bit_cast(unsigned int, f);
    u += 0x7FFFu + ((u >> 16) & 1u);   // RNE
    return (u16)(u >> 16);
}

// compiler-only memory fence: HW DS ops of one wave execute in order, so
// cross-lane LDS RAW within a wave needs no s_barrier — only a fence that
// stops the compiler hoisting the (different-address, cross-lane) reads.
__device__ __forceinline__ void wave_fence() {
    asm volatile("" ::: "memory");
}

// async global->LDS, 16B per lane; lds dest = wave-uniform base + lane*16
__device__ __forceinline__ void gload16(const u16* g, u16* l) {
    __builtin_amdgcn_global_load_lds(
        (const __attribute__((address_space(1))) unsigned int*)(g),
        (__attribute__((address_space(3))) unsigned int*)(l), 16, 0, 0);
}

// ---------------------------------------------------------------------------
// prep: one launch = X fp32->bf16 convert (blocks 0..8191) + 4 weight
// transposes fp32(rows x cols) -> bf16 (cols x rows) (blocks 8192..8831)
// ---------------------------------------------------------------------------
__global__ __launch_bounds__(256) void prep(
        const float* __restrict__ X,  const float* __restrict__ Wq,
        const float* __restrict__ Wk, const float* __restrict__ Wv,
        const float* __restrict__ Wo,
        u16* __restrict__ Xb, u16* __restrict__ WT, u16* __restrict__ OT)
{
    int bid = blockIdx.x;
    if (bid < 8192) {   // X convert: 8 elems / thread
        const size_t i = (size_t)bid * 256 + threadIdx.x;
        const float4* s = (const float4*)X + i * 2;
        float4 a = s[0], b = s[1];
        v8u o;
        o[0] = f2bf(a.x); o[1] = f2bf(a.y); o[2] = f2bf(a.z); o[3] = f2bf(a.w);
        o[4] = f2bf(b.x); o[5] = f2bf(b.y); o[6] = f2bf(b.z); o[7] = f2bf(b.w);
        *((v8u*)Xb + i) = o;
        return;
    }
    bid -= 8192;
    const float* src; u16* dst; int cols, bx, by;
    if (bid < 64)       { src = Wq; dst = WT;             cols = 128; bx = bid & 3;  by = bid >> 2; }
    else if (bid < 128) { src = Wk; dst = WT + 128 * 512; cols = 128; bid -= 64;  bx = bid & 3;  by = bid >> 2; }
    else if (bid < 384) { src = Wv; dst = WT + 256 * 512; cols = 512; bid -= 128; bx = bid & 15; by = bid >> 4; }
    else                { src = Wo; dst = OT;             cols = 512; bid -= 384; bx = bid & 15; by = bid >> 4; }
    __shared__ u16 tile[32][33];
    const int tx = threadIdx.x & 31, ty = threadIdx.x >> 5;
    const int c0 = bx * 32, r0 = by * 32;
    #pragma unroll
    for (int i = 0; i < 32; i += 8)
        tile[ty + i][tx] = f2bf(src[(size_t)(r0 + ty + i) * cols + c0 + tx]);
    __syncthreads();
    #pragma unroll
    for (int i = 0; i < 32; i += 8)
        dst[(size_t)(c0 + ty + i) * 512 + r0 + tx] = tile[tx][ty + i];
}

// ---------------------------------------------------------------------------
// P1/P5: MFMA bf16 GEMM, m97-style single-buffer (round-1 structure: best
// measured).  BK=64, global_load_lds width=16, XOR granule swizzle.
// Grid swizzle: super-groups of 8 A-panels per XCD.  Per XCD (bid&7), blocks
// sweep {8 panels} x {NY column-blocks} panel-fastest, so each panel is
// fetched once into that XCD's L2 and reused NY times (round-3 lesson:
// grouping ALL NY blocks of one panel adjacently collapses MLP; 8 panels in
// flight preserves it while keeping the reuse).
// MODE 0 (NY=6): write QS=softmax(Q*s)(f32) / KE=exp(K*s)(bf16) / V(bf16).
// MODE 1 (NY=4): fp32 Out.
// ---------------------------------------------------------------------------
template<int MODE, int NY>
__global__ __launch_bounds__(256) void gemm_mfma(
        const u16* __restrict__ A, const u16* __restrict__ Bt,
        float* __restrict__ Qo, u16* __restrict__ KEo,
        u16* __restrict__ Vo, float* __restrict__ OutF)
{
    __shared__ __align__(16) u16 As[128 * 64];   // row*64 + (g^(row&7))*8
    __shared__ __align__(16) u16 Bs[128 * 64];
    const int tid  = threadIdx.x;
    const int wave = tid >> 6, lane = tid & 63;
    const int wm = wave >> 1, wn = wave & 1;     // 2x2 waves, 64x64 each
    const int lm = lane & 15, quad = lane >> 4;

    // grid = 8 XCD * 4 groups * (8 panels * NY cols); panel-fastest in group
    const int bid = blockIdx.x;
    const int xcd = bid & 7, j = bid >> 3;
    const int grp = j / (8 * NY), r = j % (8 * NY);
    const int by  = r >> 3, pin = r & 7;
    const int bx  = xcd * 32 + grp * 8 + pin;
    const int gm0 = bx * 128, gn0 = by * 128;

    const int srow0 = wave * 32 + (lane >> 3);   // staging row, + r*8
    const int sg    = lane & 7;                  // staging granule position

    v4f acc[4][4];
    #pragma unroll
    for (int i = 0; i < 4; i++)
        #pragma unroll
        for (int j2 = 0; j2 < 4; j2++)
            acc[i][j2] = (v4f){0.f, 0.f, 0.f, 0.f};

    for (int kt = 0; kt < 8; ++kt) {
        const int k0 = kt * 64;
        #pragma unroll
        for (int rr = 0; rr < 4; ++rr) {
            const int row = srow0 + rr * 8;
            const int col = ((sg ^ (row & 7)) << 3) + k0;   // source k-granule
            gload16(&A [(size_t)(gm0 + row) * 512 + col], &As[(wave * 4 + rr) * 512]);
            gload16(&Bt[(size_t)(gn0 + row) * 512 + col], &Bs[(wave * 4 + rr) * 512]);
        }
        __syncthreads();
        v8bf af[2][4], bfr[2][4];
        #pragma unroll
        for (int ks = 0; ks < 2; ks++)
            #pragma unroll
            for (int mi = 0; mi < 4; mi++) {
                const int g  = ks * 4 + quad;
                const int ra = wm * 64 + mi * 16 + lm;
                const int rb = wn * 64 + mi * 16 + lm;
                af [ks][mi] = *(const v8bf*)&As[ra * 64 + ((g ^ (ra & 7)) << 3)];
                bfr[ks][mi] = *(const v8bf*)&Bs[rb * 64 + ((g ^ (rb & 7)) << 3)];
            }
        #pragma unroll
        for (int ks = 0; ks < 2; ks++)
            #pragma unroll
            for (int mi = 0; mi < 4; mi++)
                #pragma unroll
                for (int ni = 0; ni < 4; ni++)
                    acc[mi][ni] = __builtin_amdgcn_mfma_f32_16x16x32_bf16(
                                      af[ks][mi], bfr[ks][ni], acc[mi][ni], 0, 0, 0);
        __syncthreads();
    }

    if (MODE == 1) {
        #pragma unroll
        for (int mi = 0; mi < 4; mi++)
          #pragma unroll
          for (int ni = 0; ni < 4; ni++)
            #pragma unroll
            for (int i = 0; i < 4; i++) {
                int row = gm0 + wm * 64 + mi * 16 + quad * 4 + i;
                int col = gn0 + wn * 64 + ni * 16 + lm;
                OutF[(size_t)row * 512 + col] = acc[mi][ni][i];
            }
    } else if (gn0 == 0) {
        // Q block: fold the row-softmax here. For fixed (mi,ni,i) the 16 lanes
        // lm hold exactly one head's Lh=16 values -> 16-lane shfl reduce.
        #pragma unroll
        for (int mi = 0; mi < 4; mi++)
          #pragma unroll
          for (int ni = 0; ni < 4; ni++)
            #pragma unroll
            for (int i = 0; i < 4; i++) {
                int row = gm0 + wm * 64 + mi * 16 + quad * 4 + i;
                int col = wn * 64 + ni * 16 + lm;
                float qv = acc[mi][ni][i] * SCALE;
                float m = qv;
                #pragma unroll
                for (int off = 1; off < 16; off <<= 1) m = fmaxf(m, __shfl_xor(m, off));
                float e = __expf(qv - m);
                float s = e;
                #pragma unroll
                for (int off = 1; off < 16; off <<= 1) s += __shfl_xor(s, off);
                Qo[(size_t)row * 128 + col] = e / s;
            }
    } else if (gn0 == 128) {
        #pragma unroll
        for (int mi = 0; mi < 4; mi++)
          #pragma unroll
          for (int ni = 0; ni < 4; ni++)
            #pragma unroll
            for (int i = 0; i < 4; i++) {
                int row = gm0 + wm * 64 + mi * 16 + quad * 4 + i;
                int col = wn * 64 + ni * 16 + lm;
                KEo[(size_t)row * 128 + col] = f2bf(__expf(acc[mi][ni][i] * SCALE));
            }
    } else {
        #pragma unroll
        for (int mi = 0; mi < 4; mi++)
          #pragma unroll
          for (int ni = 0; ni < 4; ni++)
            #pragma unroll
            for (int i = 0; i < 4; i++) {
                int row = gm0 + wm * 64 + mi * 16 + quad * 4 + i;
                int col = gn0 + wn * 64 + ni * 16 + lm - 256;
                Vo[(size_t)row * 512 + col] = f2bf(acc[mi][ni][i]);
            }
    }
}

// ---------------------------------------------------------------------------
// P2a (MFMA): per chunk, one wave: M_c = KE^T(16x64) . V(64x64), lsum = KE^T . 1
// Waves are fully independent (disjoint LDS slabs) -> no __syncthreads;
// wave-internal DS ordering is in-order in HW, compiler fence only.
// ---------------------------------------------------------------------------
__global__ __launch_bounds__(256, 2) void chunk_sums_mfma(
        const u16* __restrict__ KE, const u16* __restrict__ V,
        float* __restrict__ Mc, float* __restrict__ AB)
{
    struct CLDS { u16 KA[16][72]; u16 VT[64][72]; };
    __shared__ __align__(16) CLDS lds[4];
    const int tid = threadIdx.x, wave = tid >> 6, lane = tid & 63;
    const int lm = lane & 15, quad = lane >> 4;
    const int ch = blockIdx.x * 4 + wave;
    const int bh = ch >> 6, c = ch & 63, b = bh >> 3, h = bh & 7;
    const int t0 = b * T_ + c * 64;
    CLDS& L = lds[wave];

    {
        const u16* kp = KE + (size_t)(t0 + lane) * L_ + h * Lh_;
        v8u k0 = *(const v8u*)kp, k1 = *(const v8u*)(kp + 8);
        #pragma unroll
        for (int l = 0; l < 8; l++) L.KA[l][lane]     = k0[l];
        #pragma unroll
        for (int l = 0; l < 8; l++) L.KA[l + 8][lane] = k1[l];
        const u16* vp = V + (size_t)(t0 + lane) * D_ + h * Dh_;
        #pragma unroll
        for (int seg = 0; seg < 8; ++seg) {
            v8u pv = *(const v8u*)(vp + seg * 8);
            #pragma unroll
            for (int j = 0; j < 8; j++) L.VT[seg * 8 + j][lane] = pv[j];
        }
    }
    wave_fence();

    v8bf ka[2];
    #pragma unroll
    for (int ki = 0; ki < 2; ki++)
        ka[ki] = *(const v8bf*)&L.KA[lm][ki * 32 + quad * 8];

    v8u onesu;
    #pragma unroll
    for (int j = 0; j < 8; j++) onesu[j] = 0x3F80;
    v8bf ones = __builtin_bit_cast(v8bf, onesu);

    v4f accL = (v4f){0.f, 0.f, 0.f, 0.f};
    accL = __builtin_amdgcn_mfma_f32_16x16x32_bf16(ka[0], ones, accL, 0, 0, 0);
    accL = __builtin_amdgcn_mfma_f32_16x16x32_bf16(ka[1], ones, accL, 0, 0, 0);

    v4f accM[4];
    #pragma unroll
    for (int nd = 0; nd < 4; nd++) accM[nd] = (v4f){0.f, 0.f, 0.f, 0.f};
    #pragma unroll
    for (int nd = 0; nd < 4; nd++)
        #pragma unroll
        for (int ki = 0; ki < 2; ki++) {
            v8bf vb = *(const v8bf*)&L.VT[nd * 16 + lm][ki * 32 + quad * 8];
            accM[nd] = __builtin_amdgcn_mfma_f32_16x16x32_bf16(ka[ki], vb, accM[nd], 0, 0, 0);
        }

    float* mcb = Mc + (size_t)ch * 1024;
    #pragma unroll
    for (int nd = 0; nd < 4; nd++)
        #pragma unroll
        for (int i = 0; i < 4; i++)
            mcb[(quad * 4 + i) * 64 + nd * 16 + lm] = accM[nd][i];
    if (lm == 0) {
        #pragma unroll
        for (int i = 0; i < 4; i++) AB[ch * 16 + quad * 4 + i] = accL[i];
    }
}

// ---------------------------------------------------------------------------
// P2b: exclusive prefix over chunks.  Preload all 64 chunk values as
// INDEPENDENT loads (latency hidden), scan in-register, store as bf16.
// 256 blocks x 256 threads.  McB must not alias Mc (type-size change).
// ---------------------------------------------------------------------------
__global__ __launch_bounds__(256) void chunk_prefix(
        const float* __restrict__ Mc, u16* __restrict__ McB,
        float* __restrict__ AB)
{
    const int bh = blockIdx.x >> 2, qq = blockIdx.x & 3;
    const int i = qq * 256 + threadIdx.x;
    const size_t base = (size_t)bh * 64 * 1024 + i;
    float v[64];
    #pragma unroll
    for (int c = 0; c < 64; ++c) v[c] = Mc[base + (size_t)c * 1024];
    float run = 0.f;
    #pragma unroll
    for (int c = 0; c < 64; ++c) {
        McB[base + (size_t)c * 1024] = f2bf(run);
        run += v[c];
    }
    if (qq == 0 && threadIdx.x < 16) {
        const int l = threadIdx.x;
        float a[64];
        #pragma unroll
        for (int c = 0; c < 64; ++c) a[c] = AB[(bh * 64 + c) * 16 + l];
        float r2 = 0.f;
        #pragma unroll
        for (int c = 0; c < 64; ++c) {
            AB[(bh * 64 + c) * 16 + l] = r2;
            r2 += a[c];
        }
    }
}

// ---------------------------------------------------------------------------
// P3 (MFMA): alpha = AB + tril.ke; qs = QS/alpha (QS pre-softmaxed in gemm0);
// P = QS.KE^T (masked); Y = QS.S_c + P.V
// Waves fully independent -> __syncthreads replaced with compiler fences
// (wave-internal DS ops are in-order in HW).
// ---------------------------------------------------------------------------
__global__ __launch_bounds__(256, 2) void intra_mfma(
        const float* __restrict__ QS, const u16* __restrict__ KE,
        const u16* __restrict__ V, const u16* __restrict__ McB,
        const float* __restrict__ AB, u16* __restrict__ Y)
{
    struct ILDS {
        union {
            struct { u16 KA[16][72]; u16 Sc[16][72]; u16 qs[64][40]; } s;
            u16 p[64][72];
        } r;
        u16 VT[64][72];
    };
    __shared__ __align__(16) ILDS lds[4];
    const int tid = threadIdx.x, wave = tid >> 6, lane = tid & 63;
    const int lm = lane & 15, quad = lane >> 4;
    const int ch = blockIdx.x * 4 + wave;
    const int bh = ch >> 6, c = ch & 63, b = bh >> 3, h = bh & 7;
    const int t0 = b * T_ + c * 64;
    ILDS& L = lds[wave];

    {
        const u16* kp = KE + (size_t)(t0 + lane) * L_ + h * Lh_;
        v8u k0 = *(const v8u*)kp, k1 = *(const v8u*)(kp + 8);
        #pragma unroll
        for (int l = 0; l < 8; l++) L.r.s.KA[l][lane]     = k0[l];
        #pragma unroll
        for (int l = 0; l < 8; l++) L.r.s.KA[l + 8][lane] = k1[l];
        const u16* vp = V + (size_t)(t0 + lane) * D_ + h * Dh_;
        #pragma unroll
        for (int seg = 0; seg < 8; ++seg) {
            v8u pv = *(const v8u*)(vp + seg * 8);
            #pragma unroll
            for (int j = 0; j < 8; j++) L.VT[seg * 8 + j][lane] = pv[j];
        }
        const u16* mcb = McB + (size_t)ch * 1024;
        #pragma unroll
        for (int l = 0; l < 16; l++)
            L.r.s.Sc[l][lane] = mcb[l * 64 + lane];
        v8u z8;
        #pragma unroll
        for (int j = 0; j < 8; j++) z8[j] = 0;
        *(v8u*)&L.r.s.qs[lane][16] = z8;
        *(v8u*)&L.r.s.qs[lane][24] = z8;
    }
    const float ab = AB[ch * 16 + lm];
    wave_fence();

    v4f acc_a[4];
    #pragma unroll
    for (int mi = 0; mi < 4; mi++) acc_a[mi] = (v4f){ab, ab, ab, ab};
    #pragma unroll
    for (int mi = 0; mi < 4; mi++)
        #pragma unroll
        for (int ki = 0; ki < 2; ki++) {
            if (ki == 1 && mi < 2) continue;
            v8u ta;
            #pragma unroll
            for (int j = 0; j < 8; j++)
                ta[j] = (ki * 32 + quad * 8 + j <= mi * 16 + lm) ? (u16)0x3F80 : (u16)0;
            v8bf kb = *(const v8bf*)&L.r.s.KA[lm][ki * 32 + quad * 8];
            acc_a[mi] = __builtin_amdgcn_mfma_f32_16x16x32_bf16(
                            __builtin_bit_cast(v8bf, ta), kb, acc_a[mi], 0, 0, 0);
        }

    #pragma unroll
    for (int mi = 0; mi < 4; mi++)
        #pragma unroll
        for (int i = 0; i < 4; i++) {
            int t = mi * 16 + quad * 4 + i;
            float qs = QS[(size_t)(t0 + t) * L_ + h * Lh_ + lm];
            L.r.s.qs[t][lm] = f2bf(qs / acc_a[mi][i]);
        }
    wave_fence();

    v8bf aq[4];
    #pragma unroll
    for (int mi = 0; mi < 4; mi++)
        aq[mi] = *(const v8bf*)&L.r.s.qs[mi * 16 + lm][quad * 8];

    v4f accP[4][4], accY[4][4];
    #pragma unroll
    for (int mi = 0; mi < 4; mi++)
        #pragma unroll
        for (int ni = 0; ni < 4; ni++) {
            accP[mi][ni] = (v4f){0.f, 0.f, 0.f, 0.f};
            accY[mi][ni] = (v4f){0.f, 0.f, 0.f, 0.f};
        }

    #pragma unroll
    for (int ni = 0; ni < 4; ni++) {
        v8u kbu;
        #pragma unroll
        for (int j = 0; j < 8; j++) kbu[j] = 0;
        if (quad < 2) {
            #pragma unroll
            for (int j = 0; j < 8; j++)
                kbu[j] = L.r.s.KA[quad * 8 + j][ni * 16 + lm];
        }
        v8bf kbf = __builtin_bit_cast(v8bf, kbu);
        #pragma unroll
        for (int mi = ni; mi < 4; mi++)
            accP[mi][ni] = __builtin_amdgcn_mfma_f32_16x16x32_bf16(
                               aq[mi], kbf, accP[mi][ni], 0, 0, 0);
    }
    #pragma unroll
    for (int nd = 0; nd < 4; nd++) {
        v8u scu;
        #pragma unroll
        for (int j = 0; j < 8; j++) scu[j] = 0;
        if (quad < 2) {
            #pragma unroll
            for (int j = 0; j < 8; j++)
                scu[j] = L.r.s.Sc[quad * 8 + j][nd * 16 + lm];
        }
        v8bf scf = __builtin_bit_cast(v8bf, scu);
        #pragma unroll
        for (int mi = 0; mi < 4; mi++)
            accY[mi][nd] = __builtin_amdgcn_mfma_f32_16x16x32_bf16(
                               aq[mi], scf, accY[mi][nd], 0, 0, 0);
    }
    wave_fence();

    #pragma unroll
    for (int mi = 0; mi < 4; mi++)
        #pragma unroll
        for (int ni = 0; ni < 4; ni++)
            #pragma unroll
            for (int i = 0; i < 4; i++) {
                int t = mi * 16 + quad * 4 + i, tp = ni * 16 + lm;
                float pv = (ni < mi) ? accP[mi][ni][i]
                          : (ni == mi ? ((tp <= t) ? accP[mi][ni][i] : 0.f) : 0.f);
                L.r.p[t][tp] = f2bf(pv);
            }
    wave_fence();

    v8bf vb[4][2];
    #pragma unroll
    for (int nd = 0; nd < 4; nd++)
        #pragma unroll
        for (int ki = 0; ki < 2; ki++)
            vb[nd][ki] = *(const v8bf*)&L.VT[nd * 16 + lm][ki * 32 + quad * 8];
    #pragma unroll
    for (int mi = 0; mi < 4; mi++)
        #pragma unroll
        for (int ki = 0; ki < 2; ki++) {
            if (ki == 1 && mi < 2) continue;
            v8bf pa = *(const v8bf*)&L.r.p[mi * 16 + lm][ki * 32 + quad * 8];
            #pragma unroll
            for (int nd = 0; nd < 4; nd++)
                accY[mi][nd] = __builtin_amdgcn_mfma_f32_16x16x32_bf16(
                                   pa, vb[nd][ki], accY[mi][nd], 0, 0, 0);
        }

    #pragma unroll
    for (int mi = 0; mi < 4; mi++)
        #pragma unroll
        for (int nd = 0; nd < 4; nd++)
            #pragma unroll
            for (int i = 0; i < 4; i++) {
                int t = mi * 16 + quad * 4 + i;
                Y[(((size_t)(c * 64 + t)) * 64 + bh) * 64 + nd * 16 + lm] =
                    f2bf(accY[mi][nd][i]);
            }
}

// ---------------------------------------------------------------------------
// P4: Z = Y^T :  Y (262144 x 64) -> Z (64 x 262144).  4 tiles per 256-thread
// block (one per wave, disjoint LDS slabs, no barrier needed).
// ---------------------------------------------------------------------------
__global__ __launch_bounds__(256) void transpose_Y(
        const u16* __restrict__ Y, u16* __restrict__ Z)
{
    __shared__ __align__(16) u16 tile[4][64][72];
    const int wave = threadIdx.x >> 6, t = threadIdx.x & 63;
    const int g = blockIdx.x * 4 + wave;
    u16 (*tl)[72] = tile[wave];
    const u16* yp = Y + (size_t)(g * 64 + t) * 64;
    #pragma unroll
    for (int seg = 0; seg < 8; ++seg)
        *(v8u*)&tl[t][seg * 8] = *(const v8u*)(yp + seg * 8);
    wave_fence();
    const int cl = t & 7, dq = t >> 3;
    #pragma unroll
    for (int p = 0; p < 8; ++p) {
        const int dh = p * 8 + dq;
        v8u pk;
        #pragma unroll
        for (int j = 0; j < 8; j++) pk[j] = tl[cl * 8 + j][dh];
        *(v8u*)&Z[(size_t)dh * 262144 + (size_t)g * 64 + cl * 8] = pk;
    }
}

// ---------------------------------------------------------------------------
extern "C" void kernel_launch(void* const* d_in, const int* in_sizes, int n_in,
                              void* d_out, int out_size, void* d_ws, size_t ws_size,
                              hipStream_t stream)
{
    (void)in_sizes; (void)n_in; (void)out_size; (void)ws_size;
    const float* X  = (const float*)d_in[0];
    const float* Wk = (const float*)d_in[1];   // dict order: X, Wk, Wq, Wv, o_proj
    const float* Wq = (const float*)d_in[2];
    const float* Wv = (const float*)d_in[3];
    const float* Wo = (const float*)d_in[4];
    float* Out = (float*)d_out;

    char* p = (char*)d_ws;
    auto alloc = [&](size_t bytes) { char* r = p; p += (bytes + 255) & ~(size_t)255; return r; };
    u16*   Xb = (u16*)  alloc((size_t)M_ * 512 * 2);
    u16*   WT = (u16*)  alloc((size_t)768 * 512 * 2);
    u16*   OT = (u16*)  alloc((size_t)512 * 512 * 2);
    u16*   V  = (u16*)  alloc((size_t)M_ * 512 * 2);
    float* Mc = (float*)alloc((size_t)4096 * 1024 * 4);   // 16.78 MB
    float* AB = (float*)alloc((size_t)4096 * 16 * 4);
    float* Q  = (float*)alloc((size_t)M_ * 128 * 4);      // QS (softmaxed), fp32
    u16*   KE = (u16*)  alloc((size_t)M_ * 128 * 2);
    u16*   Y  = (u16*)  alloc((size_t)M_ * 512 * 2);
    u16*   Z  = (u16*)Mc;   // alias: Mc+AB+Q (33.8MB) dead after intra; Z needs 33.5MB
    u16*   McB = (u16*)Xb;  // alias: Xb dead after gemm0; bf16 prefix (8.39MB)

    prep<<<8832, 256, 0, stream>>>(X, Wq, Wk, Wv, Wo, Xb, WT, OT);

    gemm_mfma<0, 6><<<1536, 256, 0, stream>>>(Xb, WT, Q, KE, V, nullptr);
    chunk_sums_mfma<<<1024, 256, 0, stream>>>(KE, V, Mc, AB);
    chunk_prefix   <<<256,  256, 0, stream>>>(Mc, McB, AB);
    intra_mfma     <<<1024, 256, 0, stream>>>(Q, KE, V, McB, AB, Y);
    transpose_Y    <<<1024, 256, 0, stream>>>(Y, Z);
    gemm_mfma<1, 4><<<1024, 256, 0, stream>>>(Z, OT, nullptr, nullptr, nullptr, Out);
}